// Round 4
// baseline (139.189 us; speedup 1.0000x reference)
//
#include <hip/hip_runtime.h>

typedef __attribute__((ext_vector_type(8)))  short short8;
typedef __attribute__((ext_vector_type(16))) float f32x16;
typedef unsigned int uint;

#define SEQ    2048
#define XPITCH 17                  // u32 per x row; 17 coprime 32 -> 2-way-max bank aliasing
#define XSZ    (64 * XPITCH)       // 1088 u32
#define KSZ    1040                // u32 per krev parity copy (elements 0..2079)
#define WSZ    (XSZ + 2 * KSZ)     // 3168 u32 = 12672 B per row (3168 % 32 == 0)
#define LDSU   (4 * WSZ + 16)      // + shared broadcast zero row; 50752 B -> 3 blocks/CU

__device__ inline uint pack_bf16_2(float lo, float hi) {
    uint ul = __float_as_uint(lo);
    uint uh = __float_as_uint(hi);
    ul = (ul + 0x7fffu + ((ul >> 16) & 1u)) >> 16;   // RNE
    uh = (uh + 0x7fffu + ((uh >> 16) & 1u)) >> 16;
    return (ul & 0xffffu) | (uh << 16);
}

#define MFMA(A, B, C) __builtin_amdgcn_mfma_f32_32x32x16_bf16( \
    __builtin_bit_cast(short8, A), __builtin_bit_cast(short8, B), C, 0, 0, 0)

// One wave per (b,d) row, 4 rows/block, 3 blocks/CU.
// Y(64x32) = sum_r shift_r(X) * T_r^T via 32x32x16 bf16 MFMA.
// B-frags are 4 consecutive u32 in a parity-matched krev copy: zero VALU.
__global__ __launch_bounds__(256, 3)
void hyena_mfma(const float* __restrict__ x, const float* __restrict__ kern,
                const float* __restrict__ bias, float* __restrict__ out)
{
    __shared__ __align__(16) uint lds[LDSU];
    char* ldsb = (char*)lds;

    const int tid = threadIdx.x;
    const int wid = tid >> 6;
    const int l   = tid & 63;
    const int n   = l & 31;        // MFMA row (A) / col (B/D)
    const int hi  = l >> 5;        // k-group half
    const int row = blockIdx.x * 4 + wid;
    const size_t rb = (size_t)row * SEQ;
    const float bv = bias[row & 2047];

    uint* xw = lds + wid * WSZ;    // [64][17] u32 bf16 x blocks
    uint* kA = xw + XSZ;           // kA[m] = (krev[2m],   krev[2m+1])
    uint* kB = kA + KSZ;           // kB[m] = (krev[2m+1], krev[2m+2]); base bank +16

    // ---- stage x row as bf16 ----
    #pragma unroll
    for (int it = 0; it < 16; ++it) {
        const int e = it * 128 + 2 * l;
        float2 v = *(const float2*)&x[rb + e];
        xw[(e >> 5) * XPITCH + ((e & 31) >> 1)] = pack_bf16_2(v.x, v.y);
    }
    // ---- stage kA: krev[j] = k[2047-j], zero for j >= 2048 ----
    #pragma unroll
    for (int it = 0; it < 16; ++it) {
        const int j = it * 128 + 2 * l;
        float2 v = *(const float2*)&kern[rb + (2046 - j)];   // (k[2046-j], k[2047-j])
        kA[j >> 1] = pack_bf16_2(v.y, v.x);                  // (krev[j], krev[j+1])
    }
    if (l < 16) kA[1024 + l] = 0u;                           // krev tail zeros
    __syncthreads();

    // ---- build kB (element-shifted copy) from kA ----
    #pragma unroll
    for (int it = 0; it < 17; ++it) {
        const int m = it * 64 + l;
        if (m < 1039) kB[m] = (kA[m] >> 16) | (kA[m + 1] << 16);
    }
    if (l == 0)   kB[1039] = 0u;
    if (tid < 16) lds[4 * WSZ + tid] = 0u;                   // shared zero row
    __syncthreads();

    // ---- per-lane bases ----
    // B-frag(r,s,m) elements: krev[st00 + 16s - 32r - 1024m], st00 = 2047-n+8hi.
    // Parity of the start is lane-constant -> pick kA/kB once; frag = u32[idx..idx+3].
    const int st00 = 2047 - n + 8 * hi;
    int vb1 = (wid * WSZ + XSZ + (st00 & 1) * KSZ + (st00 >> 1)) * 4;  // byte, T_r s0
    int vb2 = vb1 - 2048;                                              // T_{r+32} s0
    int va2 = wid * WSZ * 4 + (n + 32) * (XPITCH * 4) + 16 * hi;       // A row n-r+32
    const int vz = 4 * WSZ * 4 + 16 * hi;                              // zero row

    f32x16 acc0 = {}, acc1a = {}, acc1b = {};

    #pragma unroll 2
    for (int r = 0; r < 32; ++r) {
        const int va = (n >= r) ? (va2 - 32 * XPITCH * 4) : vz;  // A row (n-r) or zeros
        const uint4 a00 = *(const uint4*)(ldsb + va);            // A(-r,  s0)
        const uint4 a01 = *(const uint4*)(ldsb + va + 32);       // A(-r,  s1)
        const uint4 a10 = *(const uint4*)(ldsb + va2);           // A(32-r,s0)
        const uint4 a11 = *(const uint4*)(ldsb + va2 + 32);      // A(32-r,s1)

        const uint* k1 = (const uint*)(ldsb + vb1);
        const uint* k2 = (const uint*)(ldsb + vb2);
        uint4 b00, b01, b10, b11;        // consecutive u32 -> ds_read2_b32 pairs
        b00.x = k1[0]; b00.y = k1[1]; b00.z = k1[2];  b00.w = k1[3];
        b01.x = k1[8]; b01.y = k1[9]; b01.z = k1[10]; b01.w = k1[11];
        b10.x = k2[0]; b10.y = k2[1]; b10.z = k2[2];  b10.w = k2[3];
        b11.x = k2[8]; b11.y = k2[9]; b11.z = k2[10]; b11.w = k2[11];

        acc0  = MFMA(a00, b00, acc0);    // m=0 += X(-r)  * T_r^T
        acc1a = MFMA(a10, b00, acc1a);   // m=1 += X(32-r)* T_r^T
        acc0  = MFMA(a01, b01, acc0);
        acc1a = MFMA(a11, b01, acc1a);
        acc1b = MFMA(a00, b10, acc1b);   // m=1 += X(-r)  * T_{r+32}^T
        acc1b = MFMA(a01, b11, acc1b);

        va2 -= XPITCH * 4;   // shift row index -1
        vb1 -= 64;           // shift -32 krev elements = -16 u32
        vb2 -= 64;
    }

    // ---- epilogue: y[32p + n] = acc + x + bias ----
    #pragma unroll
    for (int mt = 0; mt < 2; ++mt) {
        #pragma unroll
        for (int t = 0; t < 16; ++t) {
            const int rloc = (t & 3) + 8 * (t >> 2) + 4 * hi;  // verified 32x32 C/D row map
            const int p = mt * 32 + rloc;
            const uint w = xw[p * XPITCH + (n >> 1)];
            const float xr = __uint_as_float((n & 1) ? (w & 0xffff0000u) : (w << 16));
            const float a = mt ? (acc1a[t] + acc1b[t]) : acc0[t];
            out[rb + (size_t)p * 32 + n] = a + xr + bv;
        }
    }
}

extern "C" void kernel_launch(void* const* d_in, const int* in_sizes, int n_in,
                              void* d_out, int out_size, void* d_ws, size_t ws_size,
                              hipStream_t stream) {
    const float* x    = (const float*)d_in[0];   // (4, 2048, 2048) f32
    const float* kern = (const float*)d_in[1];   // (4, 2048, 2048) f32
    const float* bias = (const float*)d_in[2];   // (2048,) f32
    float* out = (float*)d_out;                  // (4, 2048, 2048) f32

    hipLaunchKernelGGL(hyena_mfma, dim3(2048), dim3(256), 0, stream,
                       x, kern, bias, out);
}

// Round 5
// 69.801 us; speedup vs baseline: 1.9941x; 1.9941x over previous
//
#include <hip/hip_runtime.h>

typedef __attribute__((ext_vector_type(8)))  short short8;
typedef __attribute__((ext_vector_type(16))) float f32x16;
typedef unsigned int uint;

#define SEQ    2048
#define XPITCH 20            // u32 per x row = 80 B: 16B-aligned rows -> true ds_read_b128
#define C0OFF  1280          // krev copy shift 0 (pairs 2m+0,2m+1), len 1044 u32
#define C1OFF  2324          // shift 1, len 1040
#define C2OFF  3364          // shift 2
#define C3OFF  4404          // shift 3
#define ZOFF   5444          // 16-u32 shared zero row (broadcast reads)
#define LDSU   5460          // 21840 B -> 7 blocks/CU

__device__ inline uint pack2(float lo, float hi_) {
    uint ul = __float_as_uint(lo), uh = __float_as_uint(hi_);
    ul = (ul + 0x7fffu + ((ul >> 16) & 1u)) >> 16;   // RNE f32->bf16
    uh = (uh + 0x7fffu + ((uh >> 16) & 1u)) >> 16;
    return (ul & 0xffffu) | (uh << 16);
}

#define MFMA(A, B, C) __builtin_amdgcn_mfma_f32_32x32x16_bf16( \
    __builtin_bit_cast(short8, A), __builtin_bit_cast(short8, B), C, 0, 0, 0)

// One 64-thread block (single wave) per (b,d) row; barrier-free, wave-private LDS.
// Y(64x32) = sum_r shift_r(X) * T_r^T via 32x32x16 bf16 MFMA.
// 4 element-shifted krev copies make every B-frag 4 consecutive u32 at an EVEN
// u32 index -> provable ds_read_b64, zero select/funnel VALU.
__global__ __launch_bounds__(64, 2)
void hyena_mfma(const float* __restrict__ x, const float* __restrict__ kern,
                const float* __restrict__ bias, float* __restrict__ out)
{
    __shared__ __align__(16) uint lds[LDSU];
    char* ldsb = (char*)lds;

    const int l  = threadIdx.x;        // 0..63
    const int n  = l & 31;             // MFMA row (A) / col (B/D)
    const int hi = l >> 5;             // k-group half
    const int row = blockIdx.x;        // b*2048 + d
    const size_t rb = (size_t)row * SEQ;
    const float bv = bias[row & 2047];

    // ---- stage x row as bf16: [64 blocks][20 u32], rows 16B-aligned ----
    #pragma unroll
    for (int it = 0; it < 8; ++it) {
        const int e = it * 256 + 4 * l;
        float4 v = *(const float4*)&x[rb + e];
        uint2 w; w.x = pack2(v.x, v.y); w.y = pack2(v.z, v.w);
        *(uint2*)&lds[(e >> 5) * XPITCH + ((e & 31) >> 1)] = w;
    }

    // ---- stage 4 krev parity copies from registers ----
    // kr[i] = k[2047-i]; copy_c[m] = (kr[2m+c], kr[2m+c+1])
    #pragma unroll
    for (int it = 0; it < 4; ++it) {
        const int j = it * 512 + 8 * l;                       // 0..2040 step 8
        const float* kp0 = &kern[rb + (j == 2040 ? 0 : (2036 - j))];
        const float* kp1 = &kern[rb + (2040 - j)];            // >= rb, 16B-aligned
        float4 f0 = *(const float4*)kp0;                      // (kr[j+11..j+8]) desc
        float4 f1 = *(const float4*)kp1;                      // (kr[j+7..j+4]) desc
        float4 f2 = *(const float4*)(kp1 + 4);                // (kr[j+3..j]) desc
        if (j == 2040) { f0.x = 0.f; f0.y = 0.f; f0.z = 0.f; f0.w = 0.f; }
        const float k0 = f2.w, k1 = f2.z, k2 = f2.y, k3 = f2.x;
        const float k4 = f1.w, k5 = f1.z, k6 = f1.y, k7 = f1.x;
        const float k8 = f0.w, k9 = f0.z, k10 = f0.y;
        const int m = j >> 1;                                 // mult of 4 -> 16B aligned
        uint4 w0 = {pack2(k0,k1), pack2(k2,k3), pack2(k4,k5), pack2(k6,k7)};
        uint4 w1 = {pack2(k1,k2), pack2(k3,k4), pack2(k5,k6), pack2(k7,k8)};
        uint4 w2 = {pack2(k2,k3), pack2(k4,k5), pack2(k6,k7), pack2(k8,k9)};
        uint4 w3 = {pack2(k3,k4), pack2(k5,k6), pack2(k7,k8), pack2(k9,k10)};
        *(uint4*)&lds[C0OFF + m] = w0;
        *(uint4*)&lds[C1OFF + m] = w1;
        *(uint4*)&lds[C2OFF + m] = w2;
        *(uint4*)&lds[C3OFF + m] = w3;
    }
    // tails (elements >= 2048 are zero) + shared zero row
    if (l < 20) lds[C0OFF + 1024 + l] = 0u;
    if (l < 16) {
        lds[C1OFF + 1024 + l] = 0u;
        lds[C2OFF + 1024 + l] = 0u;
        lds[C3OFF + 1024 + l] = 0u;
        lds[ZOFF + l] = 0u;
    }

    // ---- per-lane bases ----
    // B-frag(r,s,tile) start element: st00 + 16s - 32r (- 1024), st00 = 2047-n+8hi.
    // copy c = st00&3 -> u32 index (st-c)/2 is EVEN -> 8B-aligned b64 reads.
    const int st00 = 2047 - n + 8 * hi;
    const int c    = st00 & 3;
    const int coff = (c == 0) ? C0OFF : (C0OFF + 4 + 1040 * c);   // 1280/2324/3364/4404
    int kb  = (coff + ((st00 - c) >> 1)) * 4 - 2048;  // byte; frags at +2048,+2080,+0,+32
    int va2 = (n + 32) * 80 + 16 * hi;                // byte addr of A row (n+32-r)
    const int vzb = ZOFF * 4 + 16 * hi;               // zero row (broadcast)

    f32x16 acc0 = {}, acc1a = {}, acc1b = {};

    #pragma unroll 2
    for (int r = 0; r < 32; ++r) {
        const int va = (n >= r) ? (va2 - 2560) : vzb;        // A row (n-r) or zeros
        uint4 a00 = *(const uint4*)(ldsb + va);              // A(-r,  s0)
        uint4 a01 = *(const uint4*)(ldsb + va + 32);         // A(-r,  s1)
        uint4 a10 = *(const uint4*)(ldsb + va2);             // A(32-r,s0)
        uint4 a11 = *(const uint4*)(ldsb + va2 + 32);        // A(32-r,s1)

        uint2 p0 = *(const uint2*)(ldsb + kb + 2048);        // T_r s0
        uint2 p1 = *(const uint2*)(ldsb + kb + 2056);
        uint2 p2 = *(const uint2*)(ldsb + kb + 2080);        // T_r s1
        uint2 p3 = *(const uint2*)(ldsb + kb + 2088);
        uint2 p4 = *(const uint2*)(ldsb + kb);               // T_{r+32} s0
        uint2 p5 = *(const uint2*)(ldsb + kb + 8);
        uint2 p6 = *(const uint2*)(ldsb + kb + 32);          // T_{r+32} s1
        uint2 p7 = *(const uint2*)(ldsb + kb + 40);
        uint4 b00 = {p0.x, p0.y, p1.x, p1.y};
        uint4 b01 = {p2.x, p2.y, p3.x, p3.y};
        uint4 b10 = {p4.x, p4.y, p5.x, p5.y};
        uint4 b11 = {p6.x, p6.y, p7.x, p7.y};

        acc0  = MFMA(a00, b00, acc0);    // tile0 += X(-r)   * T_r^T
        acc1a = MFMA(a10, b00, acc1a);   // tile1 += X(32-r) * T_r^T
        acc0  = MFMA(a01, b01, acc0);
        acc1a = MFMA(a11, b01, acc1a);
        acc1b = MFMA(a00, b10, acc1b);   // tile1 += X(-r)   * T_{r+32}^T
        acc1b = MFMA(a01, b11, acc1b);

        va2 -= 80;       // row shift -1
        kb  -= 64;       // -32 krev elements = -16 u32
    }

    // ---- epilogue: y[32p + n] = acc + x(bf16) + bias ----
    #pragma unroll
    for (int mt = 0; mt < 2; ++mt) {
        #pragma unroll
        for (int t = 0; t < 16; ++t) {
            const int rloc = (t & 3) + 8 * (t >> 2) + 4 * hi;  // verified 32x32 C/D map
            const int p = mt * 32 + rloc;
            const uint w = lds[p * XPITCH + (n >> 1)];
            const float xr = __uint_as_float((n & 1) ? (w & 0xffff0000u) : (w << 16));
            const float av = mt ? (acc1a[t] + acc1b[t]) : acc0[t];
            out[rb + (size_t)p * 32 + n] = av + xr + bv;
        }
    }
}

extern "C" void kernel_launch(void* const* d_in, const int* in_sizes, int n_in,
                              void* d_out, int out_size, void* d_ws, size_t ws_size,
                              hipStream_t stream) {
    const float* x    = (const float*)d_in[0];   // (4, 2048, 2048) f32
    const float* kern = (const float*)d_in[1];   // (4, 2048, 2048) f32
    const float* bias = (const float*)d_in[2];   // (2048,) f32
    float* out = (float*)d_out;                  // (4, 2048, 2048) f32

    hipLaunchKernelGGL(hyena_mfma, dim3(4 * 2048), dim3(64), 0, stream,
                       x, kern, bias, out);
}

// Round 6
// 67.661 us; speedup vs baseline: 2.0571x; 1.0316x over previous
//
#include <hip/hip_runtime.h>

typedef __attribute__((ext_vector_type(8)))  short short8;
typedef __attribute__((ext_vector_type(16))) float f32x16;
typedef unsigned int uint;

#define SEQ   2048
#define KB0   1024                 // x flat: u32 [0,1024); then 4 krev copies
#define KSTR  1048                 // copy stride (>=1038 needed); bases mod 32 = 0,24,16,8
#define ZB    (KB0 + 4 * KSTR)     // 5216: 32-u32 zero region (broadcast reads)
#define LDSU  (ZB + 32)            // 5248 u32 = 20992 B -> 7 blocks/CU

__device__ inline uint pack2(float lo, float hi_) {
    uint ul = __float_as_uint(lo), uh = __float_as_uint(hi_);
    ul = (ul + 0x7fffu + ((ul >> 16) & 1u)) >> 16;   // RNE f32->bf16
    uh = (uh + 0x7fffu + ((uh >> 16) & 1u)) >> 16;
    return (ul & 0xffffu) | (uh << 16);
}

// XOR-swizzle on x u32 index: bits 2-4 ^= bits 5-7 (bijective, b128-safe:
// bits 0-1 untouched, bits 2-4 constant within any 4-aligned group).
__device__ inline int swz(int v) { return v ^ ((v >> 3) & 28); }

#define MFMA(A, B, C) __builtin_amdgcn_mfma_f32_32x32x16_bf16( \
    __builtin_bit_cast(short8, A), __builtin_bit_cast(short8, B), C, 0, 0, 0)

// One 64-thread block (single wave) per (b,d) row; barrier-free wave-private LDS.
// Y(64x32) = sum_r shift_r(X) * T_r^T via 32x32x16 bf16 MFMA.
// x is a FLAT swizzled bf16 array (A-frag = 8 consecutive elements, u32 idx % 4 == 0);
// 4 element-shifted krev copies give 8B-aligned consecutive-u32 B-frags.
__global__ __launch_bounds__(64, 2)
void hyena_mfma(const float* __restrict__ x, const float* __restrict__ kern,
                const float* __restrict__ bias, float* __restrict__ out)
{
    __shared__ __align__(16) uint lds[LDSU];
    char* ldsb = (char*)lds;

    const int l  = threadIdx.x;        // 0..63
    const int n  = l & 31;             // MFMA row (A) / col (B/D)
    const int hi = l >> 5;             // k-group half
    const int row = blockIdx.x;        // b*2048 + d
    const size_t rb = (size_t)row * SEQ;
    const float bv = bias[row & 2047];

    // ---- stage x flat as bf16, swizzled ----
    #pragma unroll
    for (int it = 0; it < 8; ++it) {
        const int e = it * 256 + 4 * l;            // element index, 4 per lane
        float4 v = *(const float4*)&x[rb + e];
        uint2 w; w.x = pack2(v.x, v.y); w.y = pack2(v.z, v.w);
        *(uint2*)&lds[swz(e >> 1)] = w;            // swz keeps uint2 contiguous
    }

    // ---- stage 4 krev parity copies from registers ----
    // kr[i] = k[2047-i]; copy_c[m] = (kr[2m+c], kr[2m+c+1])
    #pragma unroll
    for (int it = 0; it < 4; ++it) {
        const int j = it * 512 + 8 * l;                       // 0..2040 step 8
        const float* kp0 = &kern[rb + (j == 2040 ? 0 : (2036 - j))];
        const float* kp1 = &kern[rb + (2040 - j)];            // >= rb, 16B-aligned
        float4 f0 = *(const float4*)kp0;                      // (kr[j+11..j+8]) desc
        float4 f1 = *(const float4*)kp1;                      // (kr[j+7..j+4]) desc
        float4 f2 = *(const float4*)(kp1 + 4);                // (kr[j+3..j]) desc
        if (j == 2040) { f0.x = 0.f; f0.y = 0.f; f0.z = 0.f; f0.w = 0.f; }
        const float k0 = f2.w, k1 = f2.z, k2 = f2.y, k3 = f2.x;
        const float k4 = f1.w, k5 = f1.z, k6 = f1.y, k7 = f1.x;
        const float k8 = f0.w, k9 = f0.z, k10 = f0.y;
        const int m = j >> 1;                                 // mult of 4 -> 16B aligned
        uint4 w0 = {pack2(k0,k1), pack2(k2,k3), pack2(k4,k5), pack2(k6,k7)};
        uint4 w1 = {pack2(k1,k2), pack2(k3,k4), pack2(k5,k6), pack2(k7,k8)};
        uint4 w2 = {pack2(k2,k3), pack2(k4,k5), pack2(k6,k7), pack2(k8,k9)};
        uint4 w3 = {pack2(k3,k4), pack2(k5,k6), pack2(k7,k8), pack2(k9,k10)};
        *(uint4*)&lds[KB0 + m]            = w0;
        *(uint4*)&lds[KB0 + KSTR + m]     = w1;
        *(uint4*)&lds[KB0 + 2 * KSTR + m] = w2;
        *(uint4*)&lds[KB0 + 3 * KSTR + m] = w3;
    }
    // copy tails (elements >= 2048 are zero; reads reach m=1037) + zero region
    if (l < 16) {
        lds[KB0 + 1024 + l]            = 0u;
        lds[KB0 + KSTR + 1024 + l]     = 0u;
        lds[KB0 + 2 * KSTR + 1024 + l] = 0u;
        lds[KB0 + 3 * KSTR + 1024 + l] = 0u;
    }
    if (l < 32) lds[ZB + l] = 0u;

    // ---- per-lane bases ----
    // B-frag(r,s,tile) start element: st00 + 16s - 32r (- 1024), st00 = 2047-n+8hi.
    // copy c = st00&3 -> u32 index (st-c)/2 is EVEN -> 8B-aligned b64 reads.
    const int st00 = 2047 - n + 8 * hi;
    const int c    = st00 & 3;
    int kb = (KB0 + c * KSTR + ((st00 - c) >> 1)) * 4 - 2048;  // byte
    // A-frag(r,s,tile): 8 consecutive x elements at 32(n-r)+16s+8hi (+1024 tile1)
    int ua = 16 * n + 4 * hi;                     // u32 idx, tile0 s0, r=0
    const int zb0 = ZB * 4 + 16 * hi;             // zero region (broadcast)

    f32x16 acc0 = {}, acc1a = {}, acc1b = {};

    #pragma unroll 2
    for (int r = 0; r < 32; ++r) {
        const int b0  = swz(ua) * 4;              // may be garbage if n<r (unselected)
        const int b0s = swz(ua + 8) * 4;
        const int b1  = swz(ua + 512) * 4;
        const int b1s = swz(ua + 520) * 4;
        const int va0  = (n >= r) ? b0  : zb0;
        const int va0s = (n >= r) ? b0s : (zb0 + 32);
        uint4 a00 = *(const uint4*)(ldsb + va0);             // A(-r,  s0)
        uint4 a01 = *(const uint4*)(ldsb + va0s);            // A(-r,  s1)
        uint4 a10 = *(const uint4*)(ldsb + b1);              // A(32-r,s0)
        uint4 a11 = *(const uint4*)(ldsb + b1s);             // A(32-r,s1)

        uint2 p0 = *(const uint2*)(ldsb + kb + 2048);        // T_r s0
        uint2 p1 = *(const uint2*)(ldsb + kb + 2056);
        uint2 p2 = *(const uint2*)(ldsb + kb + 2080);        // T_r s1
        uint2 p3 = *(const uint2*)(ldsb + kb + 2088);
        uint2 p4 = *(const uint2*)(ldsb + kb);               // T_{r+32} s0
        uint2 p5 = *(const uint2*)(ldsb + kb + 8);
        uint2 p6 = *(const uint2*)(ldsb + kb + 32);          // T_{r+32} s1
        uint2 p7 = *(const uint2*)(ldsb + kb + 40);
        uint4 b00 = {p0.x, p0.y, p1.x, p1.y};
        uint4 b01 = {p2.x, p2.y, p3.x, p3.y};
        uint4 b10 = {p4.x, p4.y, p5.x, p5.y};
        uint4 b11 = {p6.x, p6.y, p7.x, p7.y};

        acc0  = MFMA(a00, b00, acc0);    // tile0 += X(-r)   * T_r^T
        acc1a = MFMA(a10, b00, acc1a);   // tile1 += X(32-r) * T_r^T
        acc0  = MFMA(a01, b01, acc0);
        acc1a = MFMA(a11, b01, acc1a);
        acc1b = MFMA(a00, b10, acc1b);   // tile1 += X(-r)   * T_{r+32}^T
        acc1b = MFMA(a01, b11, acc1b);

        ua -= 16;        // shift: -32 x elements
        kb -= 64;        // shift: -32 krev elements = -16 u32
    }

    // ---- epilogue: y[32p + n] = acc + x(bf16) + bias ----
    #pragma unroll
    for (int mt = 0; mt < 2; ++mt) {
        #pragma unroll
        for (int t = 0; t < 16; ++t) {
            const int rloc = (t & 3) + 8 * (t >> 2) + 4 * hi;  // verified 32x32 C/D map
            const int p = mt * 32 + rloc;
            const uint w = lds[swz(16 * p + (n >> 1))];
            const float xr = __uint_as_float((n & 1) ? (w & 0xffff0000u) : (w << 16));
            const float av = mt ? (acc1a[t] + acc1b[t]) : acc0[t];
            out[rb + (size_t)p * 32 + n] = av + xr + bv;
        }
    }
}

extern "C" void kernel_launch(void* const* d_in, const int* in_sizes, int n_in,
                              void* d_out, int out_size, void* d_ws, size_t ws_size,
                              hipStream_t stream) {
    const float* x    = (const float*)d_in[0];   // (4, 2048, 2048) f32
    const float* kern = (const float*)d_in[1];   // (4, 2048, 2048) f32
    const float* bias = (const float*)d_in[2];   // (2048,) f32
    float* out = (float*)d_out;                  // (4, 2048, 2048) f32

    hipLaunchKernelGGL(hyena_mfma, dim3(4 * 2048), dim3(64), 0, stream,
                       x, kern, bias, out);
}

// Round 7
// 60.632 us; speedup vs baseline: 2.2956x; 1.1159x over previous
//
#include <hip/hip_runtime.h>

typedef __attribute__((ext_vector_type(8)))  short short8;
typedef __attribute__((ext_vector_type(16))) float f32x16;
typedef unsigned int uint;

#define SEQ   2048
#define KB0   1024                 // x flat: u32 [0,1024); then 4 krev copies
#define KSTR  1048                 // copy stride (>=1040 needed); bases mod 32 = 0,24,16,8
#define ZB    (KB0 + 4 * KSTR)     // 5216: 32-u32 zero region (broadcast reads)
#define LDSU  (ZB + 32)            // 5248 u32 = 20992 B -> 7 blocks/CU
#define EX0   KB0                  // exchange areas (reuse k-copy region post-barrier)
#define EX1   (KB0 + 1344)         // 64 lanes * stride 20 = 1280 u32 each

__device__ inline uint pack2(float lo, float hi_) {
    uint ul = __float_as_uint(lo), uh = __float_as_uint(hi_);
    ul = (ul + 0x7fffu + ((ul >> 16) & 1u)) >> 16;   // RNE f32->bf16
    uh = (uh + 0x7fffu + ((uh >> 16) & 1u)) >> 16;
    return (ul & 0xffffu) | (uh << 16);
}

// XOR-swizzle on x u32 index: bits 2-4 ^= bits 5-7 (bijective, b128-safe).
__device__ inline int swz(int v) { return v ^ ((v >> 3) & 28); }

#define MFMA(A, B, C) __builtin_amdgcn_mfma_f32_32x32x16_bf16( \
    __builtin_bit_cast(short8, A), __builtin_bit_cast(short8, B), C, 0, 0, 0)

// One 128-thread block (2 waves) per (b,d) row. Wave wv computes r = 16*wv .. 16*wv+15
// of Y(64x32) = sum_r shift_r(X) * T_r^T (32x32x16 bf16 MFMA), then the two waves
// exchange partial accumulators through LDS and each writes one 32-row output tile.
__global__ __launch_bounds__(128, 3)
void hyena_mfma(const float* __restrict__ x, const float* __restrict__ kern,
                const float* __restrict__ bias, float* __restrict__ out)
{
    __shared__ __align__(16) uint lds[LDSU];
    char* ldsb = (char*)lds;

    const int tid = threadIdx.x;       // 0..127
    const int wv  = tid >> 6;          // wave id 0,1
    const int l   = tid & 63;
    const int n   = l & 31;            // MFMA row (A) / col (B/D)
    const int hi  = l >> 5;            // k-group half
    const int row = blockIdx.x;        // b*2048 + d
    const size_t rb = (size_t)row * SEQ;
    const float bv = bias[row & 2047];

    // ---- stage x flat as bf16, swizzled (128 threads cooperatively) ----
    #pragma unroll
    for (int it = 0; it < 4; ++it) {
        const int e = it * 512 + 4 * tid;          // 0..2044 step 4
        float4 v = *(const float4*)&x[rb + e];
        uint2 w2; w2.x = pack2(v.x, v.y); w2.y = pack2(v.z, v.w);
        *(uint2*)&lds[swz(e >> 1)] = w2;
    }

    // ---- stage 4 krev parity copies from registers ----
    // kr[i] = k[2047-i]; copy_c[m] = (kr[2m+c], kr[2m+c+1])
    #pragma unroll
    for (int it = 0; it < 2; ++it) {
        const int j = it * 1024 + 8 * tid;                    // 0..2040 step 8
        const float* kp0 = &kern[rb + (j == 2040 ? 0 : (2036 - j))];
        const float* kp1 = &kern[rb + (2040 - j)];            // >= rb, 16B-aligned
        float4 f0 = *(const float4*)kp0;                      // (kr[j+11..j+8]) desc
        float4 f1 = *(const float4*)kp1;                      // (kr[j+7..j+4]) desc
        float4 f2 = *(const float4*)(kp1 + 4);                // (kr[j+3..j]) desc
        if (j == 2040) { f0.x = 0.f; f0.y = 0.f; f0.z = 0.f; f0.w = 0.f; }
        const float k0 = f2.w, k1 = f2.z, k2 = f2.y, k3 = f2.x;
        const float k4 = f1.w, k5 = f1.z, k6 = f1.y, k7 = f1.x;
        const float k8 = f0.w, k9 = f0.z, k10 = f0.y;
        const int m = j >> 1;                                 // mult of 4 -> 16B aligned
        uint4 w0 = {pack2(k0,k1), pack2(k2,k3), pack2(k4,k5), pack2(k6,k7)};
        uint4 w1 = {pack2(k1,k2), pack2(k3,k4), pack2(k5,k6), pack2(k7,k8)};
        uint4 w2 = {pack2(k2,k3), pack2(k4,k5), pack2(k6,k7), pack2(k8,k9)};
        uint4 w3 = {pack2(k3,k4), pack2(k5,k6), pack2(k7,k8), pack2(k9,k10)};
        *(uint4*)&lds[KB0 + m]            = w0;
        *(uint4*)&lds[KB0 + KSTR + m]     = w1;
        *(uint4*)&lds[KB0 + 2 * KSTR + m] = w2;
        *(uint4*)&lds[KB0 + 3 * KSTR + m] = w3;
    }
    if (tid < 16) {                    // copy tails (elements >= 2048 are zero)
        lds[KB0 + 1024 + tid]            = 0u;
        lds[KB0 + KSTR + 1024 + tid]     = 0u;
        lds[KB0 + 2 * KSTR + 1024 + tid] = 0u;
        lds[KB0 + 3 * KSTR + 1024 + tid] = 0u;
    }
    if (tid < 32) lds[ZB + tid] = 0u;  // shared zero region
    __syncthreads();

    // ---- per-lane bases (wave wv starts at r = R0) ----
    const int R0   = wv << 4;
    const int st00 = 2047 - n + 8 * hi;
    const int c    = st00 & 3;
    int kb = (KB0 + c * KSTR + ((st00 - c) >> 1)) * 4 - 2048 - (R0 << 6);
    int ua = 16 * n + 4 * hi - (R0 << 4);         // u32 idx, tile0 s0
    const int zb0 = ZB * 4 + 16 * hi;             // zero region (broadcast)

    f32x16 acc0 = {}, acc1a = {}, acc1b = {};

    #pragma unroll 2
    for (int i = 0; i < 16; ++i) {
        const int r = R0 + i;
        const int b0  = swz(ua) * 4;              // garbage if n<r (unselected)
        const int b0s = swz(ua + 8) * 4;
        const int b1  = swz(ua + 512) * 4;
        const int b1s = swz(ua + 520) * 4;
        const int va0  = (n >= r) ? b0  : zb0;
        const int va0s = (n >= r) ? b0s : (zb0 + 32);
        uint4 a00 = *(const uint4*)(ldsb + va0);             // A(-r,  s0)
        uint4 a01 = *(const uint4*)(ldsb + va0s);            // A(-r,  s1)
        uint4 a10 = *(const uint4*)(ldsb + b1);              // A(32-r,s0)
        uint4 a11 = *(const uint4*)(ldsb + b1s);             // A(32-r,s1)

        uint2 p0 = *(const uint2*)(ldsb + kb + 2048);        // T_r s0
        uint2 p1 = *(const uint2*)(ldsb + kb + 2056);
        uint2 p2 = *(const uint2*)(ldsb + kb + 2080);        // T_r s1
        uint2 p3 = *(const uint2*)(ldsb + kb + 2088);
        uint2 p4 = *(const uint2*)(ldsb + kb);               // T_{r+32} s0
        uint2 p5 = *(const uint2*)(ldsb + kb + 8);
        uint2 p6 = *(const uint2*)(ldsb + kb + 32);          // T_{r+32} s1
        uint2 p7 = *(const uint2*)(ldsb + kb + 40);
        uint4 b00 = {p0.x, p0.y, p1.x, p1.y};
        uint4 b01 = {p2.x, p2.y, p3.x, p3.y};
        uint4 b10 = {p4.x, p4.y, p5.x, p5.y};
        uint4 b11 = {p6.x, p6.y, p7.x, p7.y};

        acc0  = MFMA(a00, b00, acc0);    // tile0 += X(-r)   * T_r^T
        acc1a = MFMA(a10, b00, acc1a);   // tile1 += X(32-r) * T_r^T
        acc0  = MFMA(a01, b01, acc0);
        acc1a = MFMA(a11, b01, acc1a);
        acc1b = MFMA(a00, b10, acc1b);   // tile1 += X(-r)   * T_{r+32}^T
        acc1b = MFMA(a01, b11, acc1b);

        ua -= 16;        // shift: -32 x elements
        kb -= 64;        // shift: -32 krev elements = -16 u32
    }
    __syncthreads();     // all k reads done before exchange overwrites copies

    // ---- cross-wave partial exchange (reuse k-copy region) ----
    f32x16 part_send, part_keep;
    if (wv == 0) { part_send = acc1a + acc1b; part_keep = acc0; }
    else         { part_send = acc0;          part_keep = acc1a + acc1b; }
    const int exw = (wv == 0) ? EX0 : EX1;
    const int exr = (wv == 0) ? EX1 : EX0;
    #pragma unroll
    for (int q = 0; q < 4; ++q) {
        float4 f = {part_send[4*q], part_send[4*q+1], part_send[4*q+2], part_send[4*q+3]};
        *(float4*)(ldsb + 4 * (exw + l * 20) + 16 * q) = f;
    }
    __syncthreads();
    f32x16 tile = part_keep;
    #pragma unroll
    for (int q = 0; q < 4; ++q) {
        float4 f = *(const float4*)(ldsb + 4 * (exr + l * 20) + 16 * q);
        tile[4*q] += f.x; tile[4*q+1] += f.y; tile[4*q+2] += f.z; tile[4*q+3] += f.w;
    }

    // ---- epilogue: wave wv writes tile wv; y[32p + n] = acc + x(bf16) + bias ----
    #pragma unroll
    for (int t = 0; t < 16; ++t) {
        const int rloc = (t & 3) + 8 * (t >> 2) + 4 * hi;  // verified 32x32 C/D map
        const int p = 32 * wv + rloc;
        const uint w = lds[swz(16 * p + (n >> 1))];
        const float xr = __uint_as_float((n & 1) ? (w & 0xffff0000u) : (w << 16));
        out[rb + (size_t)p * 32 + n] = tile[t] + xr + bv;
    }
}

extern "C" void kernel_launch(void* const* d_in, const int* in_sizes, int n_in,
                              void* d_out, int out_size, void* d_ws, size_t ws_size,
                              hipStream_t stream) {
    const float* x    = (const float*)d_in[0];   // (4, 2048, 2048) f32
    const float* kern = (const float*)d_in[1];   // (4, 2048, 2048) f32
    const float* bias = (const float*)d_in[2];   // (2048,) f32
    float* out = (float*)d_out;                  // (4, 2048, 2048) f32

    hipLaunchKernelGGL(hyena_mfma, dim3(4 * 2048), dim3(128), 0, stream,
                       x, kern, bias, out);
}